// Round 5
// baseline (545.791 us; speedup 1.0000x reference)
//
#include <hip/hip_runtime.h>

#define NN 50000
#define NE 800000
#define INC 32
#define HH 64
#define H2 128
#define OC 16
#define ON 17
#define NL 4
#define MEPS 1e-7f
#define LNE 1e-5f
#define SCAN_BLOCKS 196   /* ceil(50000/256) */

// ---------- ordered-uint encoding for float atomic max ----------
__device__ __forceinline__ unsigned fenc(float x) {
    unsigned u = __float_as_uint(x);
    return (u & 0x80000000u) ? ~u : (u | 0x80000000u);
}
__device__ __forceinline__ float fdec(unsigned u) {
    return (u & 0x80000000u) ? __uint_as_float(u & 0x7fffffffu)
                             : __uint_as_float(~u);
}
// ---------- bf16 helpers (RNE) ----------
__device__ __forceinline__ unsigned short f2b(float x) {
    unsigned b = __float_as_uint(x);
    b += 0x7FFFu + ((b >> 16) & 1u);
    return (unsigned short)(b >> 16);
}
__device__ __forceinline__ float b2f(unsigned short u) {
    return __uint_as_float(((unsigned)u) << 16);
}

// ---------- CSR build ----------
__global__ __launch_bounds__(256) void k_hist2(const int* __restrict__ dst, int* __restrict__ counts,
                                               int* __restrict__ rank) {
    int e = blockIdx.x * 256 + threadIdx.x;
    if (e < NE) rank[e] = atomicAdd(&counts[dst[e]], 1);
}

__global__ __launch_bounds__(256) void k_scan1(const int* __restrict__ counts,
                                               int* __restrict__ incl, int* __restrict__ bsums) {
    __shared__ int s[256];
    int t = threadIdx.x;
    int i = blockIdx.x * 256 + t;
    int v = (i < NN) ? counts[i] : 0;
    s[t] = v;
    __syncthreads();
    for (int off = 1; off < 256; off <<= 1) {
        int x = (t >= off) ? s[t - off] : 0;
        __syncthreads();
        s[t] += x;
        __syncthreads();
    }
    if (i < NN) incl[i] = s[t];
    if (t == 255) bsums[blockIdx.x] = s[255];
}

__global__ __launch_bounds__(256) void k_scan2(int* __restrict__ bsums) {
    __shared__ int s[256];
    int t = threadIdx.x;
    int v = (t < SCAN_BLOCKS) ? bsums[t] : 0;
    s[t] = v;
    __syncthreads();
    for (int off = 1; off < 256; off <<= 1) {
        int x = (t >= off) ? s[t - off] : 0;
        __syncthreads();
        s[t] += x;
        __syncthreads();
    }
    if (t < SCAN_BLOCKS) bsums[t] = s[t] - v;  // exclusive
}

// rowse[i] = {start, deg}
__global__ __launch_bounds__(256) void k_scan3(const int* __restrict__ counts,
                                               const int* __restrict__ incl,
                                               const int* __restrict__ bsums,
                                               int2* __restrict__ rowse) {
    int i = blockIdx.x * 256 + threadIdx.x;
    if (i < NN) {
        int c = counts[i];
        rowse[i] = make_int2(incl[i] - c + bsums[blockIdx.x], c);
    }
}

__global__ __launch_bounds__(256) void k_scatter2(const int* __restrict__ src, const int* __restrict__ dst,
                                                  const int* __restrict__ rank, const int2* __restrict__ rowse,
                                                  int* __restrict__ ssrc) {
    int e = blockIdx.x * 256 + threadIdx.x;
    if (e < NE) ssrc[rowse[dst[e]].x + rank[e]] = src[e];
}

// ---------- node encoder: h = x @ W + b  ([N,32]@[32,64]), also bf16 shadow ----------
__global__ __launch_bounds__(256) void k_encoder(const float* __restrict__ x, const float* __restrict__ W,
                                                 const float* __restrict__ b, float* __restrict__ h,
                                                 unsigned short* __restrict__ hbf) {
    __shared__ float Ws[INC * HH];
    __shared__ float bs[HH];
    int tid = threadIdx.x;
    for (int i = tid; i < INC * HH; i += 256) Ws[i] = W[i];
    if (tid < HH) bs[tid] = b[tid];
    __syncthreads();
    int wid = tid >> 6, lane = tid & 63;
    int n = blockIdx.x * 4 + wid;
    if (n >= NN) return;
    float v = (lane < INC) ? x[(size_t)n * INC + lane] : 0.f;
    float acc = bs[lane];
    #pragma unroll
    for (int k = 0; k < INC; ++k)
        acc += __shfl(v, k) * Ws[k * HH + lane];
    h[(size_t)n * HH + lane] = acc;
    hbf[(size_t)n * HH + lane] = f2b(acc);
}

// ---------- per-dst softmax aggregation ----------
// Wide gathers: lane = (slot, chan-octet); each lane loads 16 B (8 bf16 ch)
// of edge (base+slot)'s row -> one wave instr covers 8 rows with only
// 8 addresses/row (TA-throughput optimal). Slot-reduce via shfl_xor(8/16/32),
// then LDS transpose so lane = channel. Exact grid: 12500*4 == NN.
__global__ __launch_bounds__(256) void k_agg(const float* __restrict__ y,
                                             const unsigned short* __restrict__ ybf,
                                             const int2* __restrict__ rowse,
                                             const int* __restrict__ ssrc,
                                             const float* __restrict__ tp, float* __restrict__ ag) {
    __shared__ float xs[4][64];
    __shared__ float xm[4][64];
    int tid = threadIdx.x;
    int wid = tid >> 6, lane = tid & 63;
    int n = blockIdx.x * 4 + wid;
    float tval = *tp;
    int2 se = rowse[n];
    int start = se.x, deg = se.y;
    int slot = lane >> 3;
    int c = lane & 7;                 // channel octet
    float Sa[8] = {0.f, 0.f, 0.f, 0.f, 0.f, 0.f, 0.f, 0.f};
    float Sm[8] = {0.f, 0.f, 0.f, 0.f, 0.f, 0.f, 0.f, 0.f};
    if (deg > 0 && deg <= 64) {
        int myidx = (lane < deg) ? ssrc[start + lane] : 0;
        for (int base = 0; base < deg; base += 8) {
            int e = base + slot;
            int ec = (e < deg) ? e : (deg - 1);
            int s = __shfl(myidx, ec);
            uint4 v = *((const uint4*)(ybf + (size_t)s * HH) + c);
            bool ok = e < deg;
            unsigned w0 = v.x, w1 = v.y, w2 = v.z, w3 = v.w;
            unsigned wv[4] = {w0, w1, w2, w3};
            #pragma unroll
            for (int j = 0; j < 4; ++j) {
                float mlo = fmaxf(b2f((unsigned short)(wv[j] & 0xffffu)), 0.f) + MEPS;
                float mhi = fmaxf(b2f((unsigned short)(wv[j] >> 16)), 0.f) + MEPS;
                float alo = ok ? __expf(tval * mlo) : 0.f;
                float ahi = ok ? __expf(tval * mhi) : 0.f;
                Sa[2 * j] += alo;     Sm[2 * j] += mlo * alo;
                Sa[2 * j + 1] += ahi; Sm[2 * j + 1] += mhi * ahi;
            }
        }
    } else if (deg > 64) {
        for (int ob = 0; ob < deg; ob += 64) {
            int dd = deg - ob; if (dd > 64) dd = 64;
            int myidx = (lane < dd) ? ssrc[start + ob + lane] : 0;
            for (int base = 0; base < dd; base += 8) {
                int e = base + slot;
                int ec = (e < dd) ? e : (dd - 1);
                int s = __shfl(myidx, ec);
                uint4 v = *((const uint4*)(ybf + (size_t)s * HH) + c);
                bool ok = e < dd;
                unsigned wv[4] = {v.x, v.y, v.z, v.w};
                #pragma unroll
                for (int j = 0; j < 4; ++j) {
                    float mlo = fmaxf(b2f((unsigned short)(wv[j] & 0xffffu)), 0.f) + MEPS;
                    float mhi = fmaxf(b2f((unsigned short)(wv[j] >> 16)), 0.f) + MEPS;
                    float alo = ok ? __expf(tval * mlo) : 0.f;
                    float ahi = ok ? __expf(tval * mhi) : 0.f;
                    Sa[2 * j] += alo;     Sm[2 * j] += mlo * alo;
                    Sa[2 * j + 1] += ahi; Sm[2 * j + 1] += mhi * ahi;
                }
            }
        }
    }
    #pragma unroll
    for (int msk = 8; msk < 64; msk <<= 1) {
        #pragma unroll
        for (int j = 0; j < 8; ++j) {
            Sa[j] += __shfl_xor(Sa[j], msk);
            Sm[j] += __shfl_xor(Sm[j], msk);
        }
    }
    if (slot == 0) {
        #pragma unroll
        for (int j = 0; j < 8; ++j) {
            xs[wid][c * 8 + j] = Sa[j];
            xm[wid][c * 8 + j] = Sm[j];
        }
    }
    __syncthreads();
    float Saf = xs[wid][lane], Smf = xm[wid][lane];
    float agg = Smf / fmaxf(Saf, MEPS);  // deg==0 -> 0
    ag[(size_t)n * HH + lane] = agg + y[(size_t)n * HH + lane];
}

// ---------- GEMM A: U = ag @ W1 + b1  ([N,64]@[64,128]) ----------
__global__ __launch_bounds__(256) void k_gemmA(const float* __restrict__ A, const float* __restrict__ W,
                                               const float* __restrict__ bias, float* __restrict__ U) {
    __shared__ float As[64 * 68];
    __shared__ float Bs[HH * H2];
    __shared__ float bb[H2];
    int tid = threadIdx.x;
    int nb = blockIdx.x * 64;
    for (int i = tid; i < HH * H2 / 4; i += 256)
        ((float4*)Bs)[i] = ((const float4*)W)[i];
    if (tid < H2) bb[tid] = bias[tid];
    {
        int row = tid >> 2, cb = (tid & 3) * 16;
        int n = nb + row;
        float4* dp = (float4*)(As + row * 68 + cb);
        if (n < NN) {
            const float4* sp = (const float4*)(A + (size_t)n * HH + cb);
            #pragma unroll
            for (int i = 0; i < 4; ++i) dp[i] = sp[i];
        } else {
            float4 z = {0.f, 0.f, 0.f, 0.f};
            #pragma unroll
            for (int i = 0; i < 4; ++i) dp[i] = z;
        }
    }
    __syncthreads();
    int tx = tid & 15, ty = tid >> 4;
    int r0 = ty * 4, j0 = tx * 8;
    float acc[4][8] = {};
    #pragma unroll 8
    for (int k = 0; k < HH; ++k) {
        float4 b0 = *(const float4*)(Bs + k * H2 + j0);
        float4 b1 = *(const float4*)(Bs + k * H2 + j0 + 4);
        #pragma unroll
        for (int r = 0; r < 4; ++r) {
            float a = As[(r0 + r) * 68 + k];
            acc[r][0] += a * b0.x; acc[r][1] += a * b0.y;
            acc[r][2] += a * b0.z; acc[r][3] += a * b0.w;
            acc[r][4] += a * b1.x; acc[r][5] += a * b1.y;
            acc[r][6] += a * b1.z; acc[r][7] += a * b1.w;
        }
    }
    #pragma unroll
    for (int r = 0; r < 4; ++r) {
        int n = nb + r0 + r;
        if (n < NN) {
            float4 o0, o1;
            o0.x = acc[r][0] + bb[j0];     o0.y = acc[r][1] + bb[j0 + 1];
            o0.z = acc[r][2] + bb[j0 + 2]; o0.w = acc[r][3] + bb[j0 + 3];
            o1.x = acc[r][4] + bb[j0 + 4]; o1.y = acc[r][5] + bb[j0 + 5];
            o1.z = acc[r][6] + bb[j0 + 6]; o1.w = acc[r][7] + bb[j0 + 7];
            *(float4*)(U + (size_t)n * H2 + j0) = o0;
            *(float4*)(U + (size_t)n * H2 + j0 + 4) = o1;
        }
    }
}

// ---------- GEMM B: fused LN(128)+ReLU on input, +bias, +residual,
//            and fused NEXT-layer LN(64)+ReLU epilogue (y, ybf) ----------
__global__ __launch_bounds__(256) void k_gemmB(const float* __restrict__ U, const float* __restrict__ W,
                                               const float* __restrict__ bias,
                                               const float* __restrict__ lng, const float* __restrict__ lnb,
                                               const float* __restrict__ hres, float* __restrict__ hout,
                                               const float* __restrict__ nlg, const float* __restrict__ nlb,
                                               float* __restrict__ ynext, unsigned short* __restrict__ bfnext) {
    __shared__ float As[64 * 132];
    __shared__ float Bs[H2 * HH];
    __shared__ float bb[HH];
    __shared__ float lg[H2], lb[H2];
    __shared__ float ps[64 * 16], psq[64 * 16];
    __shared__ float mus[64], rss[64];
    int tid = threadIdx.x;
    int nb = blockIdx.x * 64;
    for (int i = tid; i < H2 * HH / 4; i += 256)
        ((float4*)Bs)[i] = ((const float4*)W)[i];
    if (tid < HH) bb[tid] = bias[tid];
    if (tid < H2) { lg[tid] = lng[tid]; lb[tid] = lnb[tid]; }
    {
        int row = tid >> 2, cb = (tid & 3) * 32;
        int n = nb + row;
        float4* dp = (float4*)(As + row * 132 + cb);
        if (n < NN) {
            const float4* sp = (const float4*)(U + (size_t)n * H2 + cb);
            #pragma unroll
            for (int i = 0; i < 8; ++i) dp[i] = sp[i];
        } else {
            float4 z = {0.f, 0.f, 0.f, 0.f};
            #pragma unroll
            for (int i = 0; i < 8; ++i) dp[i] = z;
        }
    }
    __syncthreads();
    {
        int row = tid >> 2, q = tid & 3;
        const float* rp = As + row * 132;
        float s = 0.f, sq = 0.f;
        #pragma unroll
        for (int i = 0; i < 32; ++i) { float v = rp[i * 4 + q]; s += v; sq += v * v; }
        ps[row * 4 + q] = s; psq[row * 4 + q] = sq;
    }
    __syncthreads();
    if (tid < 64) {
        float s = ps[tid * 4] + ps[tid * 4 + 1] + ps[tid * 4 + 2] + ps[tid * 4 + 3];
        float sq = psq[tid * 4] + psq[tid * 4 + 1] + psq[tid * 4 + 2] + psq[tid * 4 + 3];
        float mu = s * (1.f / 128.f);
        float var = sq * (1.f / 128.f) - mu * mu;
        mus[tid] = mu;
        rss[tid] = rsqrtf(fmaxf(var, 0.f) + LNE);
    }
    __syncthreads();
    {
        int row = tid >> 2, q = tid & 3;
        float mu = mus[row], rs = rss[row];
        float* rp = As + row * 132;
        #pragma unroll
        for (int i = 0; i < 32; ++i) {
            int c = i * 4 + q;
            float v = (rp[c] - mu) * rs * lg[c] + lb[c];
            rp[c] = fmaxf(v, 0.f);
        }
    }
    __syncthreads();
    int tx = tid & 15, ty = tid >> 4;
    int r0 = ty * 4, o0 = tx * 4;
    float acc[4][4] = {};
    #pragma unroll 8
    for (int k = 0; k < H2; ++k) {
        float4 b4 = *(const float4*)(Bs + k * HH + o0);
        #pragma unroll
        for (int r = 0; r < 4; ++r) {
            float a = As[(r0 + r) * 132 + k];
            acc[r][0] += a * b4.x; acc[r][1] += a * b4.y;
            acc[r][2] += a * b4.z; acc[r][3] += a * b4.w;
        }
    }
    float o[4][4];
    #pragma unroll
    for (int r = 0; r < 4; ++r) {
        int n = nb + r0 + r;
        o[r][0] = acc[r][0] + bb[o0];     o[r][1] = acc[r][1] + bb[o0 + 1];
        o[r][2] = acc[r][2] + bb[o0 + 2]; o[r][3] = acc[r][3] + bb[o0 + 3];
        if (n < NN) {
            if (hres) {
                float4 hr = *(const float4*)(hres + (size_t)n * HH + o0);
                o[r][0] += hr.x; o[r][1] += hr.y; o[r][2] += hr.z; o[r][3] += hr.w;
            }
            float4 ov = {o[r][0], o[r][1], o[r][2], o[r][3]};
            *(float4*)(hout + (size_t)n * HH + o0) = ov;
        }
    }
    if (nlg) {
        // next-layer LN(64)+ReLU on the o tile still in registers
        __syncthreads();
        #pragma unroll
        for (int r = 0; r < 4; ++r) {
            float s = o[r][0] + o[r][1] + o[r][2] + o[r][3];
            float sq = o[r][0] * o[r][0] + o[r][1] * o[r][1]
                     + o[r][2] * o[r][2] + o[r][3] * o[r][3];
            ps[(r0 + r) * 16 + tx] = s;
            psq[(r0 + r) * 16 + tx] = sq;
        }
        __syncthreads();
        if (tid < 64) {
            float s = 0.f, sq = 0.f;
            #pragma unroll
            for (int i = 0; i < 16; ++i) { s += ps[tid * 16 + i]; sq += psq[tid * 16 + i]; }
            float mu = s * (1.f / 64.f);
            float var = sq * (1.f / 64.f) - mu * mu;
            mus[tid] = mu;
            rss[tid] = rsqrtf(fmaxf(var, 0.f) + LNE);
        }
        __syncthreads();
        float g0 = nlg[o0], g1 = nlg[o0 + 1], g2 = nlg[o0 + 2], g3 = nlg[o0 + 3];
        float c0 = nlb[o0], c1 = nlb[o0 + 1], c2 = nlb[o0 + 2], c3 = nlb[o0 + 3];
        #pragma unroll
        for (int r = 0; r < 4; ++r) {
            int n = nb + r0 + r;
            if (n < NN) {
                float mu = mus[r0 + r], rs = rss[r0 + r];
                float y0 = fmaxf((o[r][0] - mu) * rs * g0 + c0, 0.f);
                float y1 = fmaxf((o[r][1] - mu) * rs * g1 + c1, 0.f);
                float y2 = fmaxf((o[r][2] - mu) * rs * g2 + c2, 0.f);
                float y3 = fmaxf((o[r][3] - mu) * rs * g3 + c3, 0.f);
                float4 yv = {y0, y1, y2, y3};
                *(float4*)(ynext + (size_t)n * HH + o0) = yv;
                ushort4 bv;
                bv.x = f2b(y0); bv.y = f2b(y1); bv.z = f2b(y2); bv.w = f2b(y3);
                *(ushort4*)(bfnext + (size_t)n * HH + o0) = bv;
            }
        }
    }
}

// ---------- fused final LN + both heads, GEMM-tile (64 nodes/block) ----------
__global__ __launch_bounds__(256) void k_outg(const float* __restrict__ h,
                                              const float* __restrict__ lng, const float* __restrict__ lnb,
                                              const float* __restrict__ gW, const float* __restrict__ gb,
                                              const float* __restrict__ nW, const float* __restrict__ nbp,
                                              float* __restrict__ dout, unsigned* __restrict__ genc) {
    __shared__ float As[64 * 68];
    __shared__ float Wc[64 * 40];
    __shared__ float Os[64 * 40];
    __shared__ float bs[40];
    __shared__ float lg[HH], lb[HH];
    __shared__ float ps[256], psq[256];
    __shared__ float mus[64], rss[64];
    int tid = threadIdx.x;
    int nb = blockIdx.x * 64;
    for (int i = tid; i < HH * ON; i += 256) { int k = i / ON, j = i - k * ON; Wc[k * 40 + j] = nW[i]; }
    for (int i = tid; i < HH * OC; i += 256) { int k = i / OC, j = i - k * OC; Wc[k * 40 + ON + j] = gW[i]; }
    if (tid < ON) bs[tid] = nbp[tid];
    else if (tid < 33) bs[tid] = gb[tid - ON];
    if (tid < HH) { lg[tid] = lng[tid]; lb[tid] = lnb[tid]; }
    {
        int row = tid >> 2, cb = (tid & 3) * 16;
        int n = nb + row;
        float4* dp = (float4*)(As + row * 68 + cb);
        if (n < NN) {
            const float4* sp = (const float4*)(h + (size_t)n * HH + cb);
            #pragma unroll
            for (int i = 0; i < 4; ++i) dp[i] = sp[i];
        } else {
            float4 z = {0.f, 0.f, 0.f, 0.f};
            #pragma unroll
            for (int i = 0; i < 4; ++i) dp[i] = z;
        }
    }
    __syncthreads();
    {
        int row = tid >> 2, q = tid & 3;
        const float* rp = As + row * 68;
        float s = 0.f, sq = 0.f;
        #pragma unroll
        for (int i = 0; i < 16; ++i) { float v = rp[q + 4 * i]; s += v; sq += v * v; }
        ps[tid] = s; psq[tid] = sq;
    }
    __syncthreads();
    if (tid < 64) {
        float s = ps[tid * 4] + ps[tid * 4 + 1] + ps[tid * 4 + 2] + ps[tid * 4 + 3];
        float sq = psq[tid * 4] + psq[tid * 4 + 1] + psq[tid * 4 + 2] + psq[tid * 4 + 3];
        float mu = s * (1.f / 64.f);
        float var = sq * (1.f / 64.f) - mu * mu;
        mus[tid] = mu;
        rss[tid] = rsqrtf(fmaxf(var, 0.f) + LNE);
    }
    __syncthreads();
    {
        int row = tid >> 2, q = tid & 3;
        float mu = mus[row], rs = rss[row];
        float* rp = As + row * 68;
        #pragma unroll
        for (int i = 0; i < 16; ++i) {
            int c = q + 4 * i;
            rp[c] = fmaxf((rp[c] - mu) * rs * lg[c] + lb[c], 0.f);
        }
    }
    __syncthreads();
    int tx = tid & 15, ty = tid >> 4;
    int r0 = ty * 4;
    float acc[4][3];
    #pragma unroll
    for (int r = 0; r < 4; ++r) {
        acc[r][0] = bs[tx]; acc[r][1] = bs[tx + 16]; acc[r][2] = bs[32];
    }
    #pragma unroll 4
    for (int k = 0; k < HH; ++k) {
        float w0 = Wc[k * 40 + tx];
        float w1 = Wc[k * 40 + 16 + tx];
        float w2 = Wc[k * 40 + 32];
        #pragma unroll
        for (int r = 0; r < 4; ++r) {
            float a = As[(r0 + r) * 68 + k];
            acc[r][0] += a * w0; acc[r][1] += a * w1; acc[r][2] += a * w2;
        }
    }
    #pragma unroll
    for (int r = 0; r < 4; ++r) {
        Os[(r0 + r) * 40 + tx] = acc[r][0];
        Os[(r0 + r) * 40 + 16 + tx] = acc[r][1];
        if (tx == 0) Os[(r0 + r) * 40 + 32] = acc[r][2];
    }
    __syncthreads();
    for (int i = tid; i < 64 * ON; i += 256) {
        int r = i / ON, j = i - r * ON;
        int n = nb + r;
        if (n < NN) dout[OC + (size_t)n * ON + j] = Os[r * 40 + j];
    }
    if (tid < OC) {
        int rmax = NN - nb; if (rmax > 64) rmax = 64;
        float m = -INFINITY;
        for (int r = 0; r < rmax; ++r) m = fmaxf(m, Os[r * 40 + ON + tid]);
        atomicMax(&genc[tid], fenc(m));
    }
}

__global__ void k_gdec(const unsigned* __restrict__ genc, float* __restrict__ dout) {
    int t = threadIdx.x;
    if (t < OC) dout[t] = fdec(genc[t]);
}

// ---------- launch ----------
extern "C" void kernel_launch(void* const* d_in, const int* in_sizes, int n_in,
                              void* d_out, int out_size, void* d_ws, size_t ws_size,
                              hipStream_t stream) {
    const float* x     = (const float*)d_in[0];
    const float* nodeW = (const float*)d_in[1];
    const float* nodeB = (const float*)d_in[2];
    const float* W1    = (const float*)d_in[3];
    const float* b1    = (const float*)d_in[4];
    const float* mlg   = (const float*)d_in[5];
    const float* mlb   = (const float*)d_in[6];
    const float* W2    = (const float*)d_in[7];
    const float* b2    = (const float*)d_in[8];
    const float* tt    = (const float*)d_in[9];
    const float* lng   = (const float*)d_in[10];
    const float* lnb   = (const float*)d_in[11];
    const int*   ei    = (const int*)d_in[12];
    const float* gW    = (const float*)d_in[13];
    const float* gb    = (const float*)d_in[14];
    const float* nW    = (const float*)d_in[15];
    const float* nbp   = (const float*)d_in[16];
    float* out = (float*)d_out;

    char* ws = (char*)d_ws;
    size_t off = 0;
    auto alloc = [&](size_t bytes) -> void* {
        void* p = ws + off;
        off = (off + bytes + 255) & ~(size_t)255;
        return p;
    };
    int* counts    = (int*)alloc((size_t)NN * 4);
    unsigned* genc = (unsigned*)alloc(64);
    size_t zero_end = off;
    int* bsums = (int*)alloc(1024);
    int* incl  = (int*)alloc((size_t)NN * 4);
    int2* rowse = (int2*)alloc((size_t)NN * 8);
    int* ssrc  = (int*)alloc((size_t)NE * 4);
    float* h   = (float*)alloc((size_t)NN * HH * 4);
    float* y   = (float*)alloc((size_t)NN * HH * 4);
    float* ag  = (float*)alloc((size_t)NN * HH * 4);
    float* u   = (float*)alloc((size_t)NN * H2 * 4);
    unsigned short* ybf = (unsigned short*)alloc((size_t)NN * HH * 2);
    int* rank = (int*)u;   // alias: rank only lives during CSR build

    const int* esrc = ei;
    const int* edst = ei + NE;

    hipMemsetAsync(d_ws, 0, zero_end, stream);

    k_hist2<<<(NE + 255) / 256, 256, 0, stream>>>(edst, counts, rank);
    k_scan1<<<SCAN_BLOCKS, 256, 0, stream>>>(counts, incl, bsums);
    k_scan2<<<1, 256, 0, stream>>>(bsums);
    k_scan3<<<SCAN_BLOCKS, 256, 0, stream>>>(counts, incl, bsums, rowse);
    k_scatter2<<<(NE + 255) / 256, 256, 0, stream>>>(esrc, edst, rank, rowse, ssrc);
    k_encoder<<<(NN + 3) / 4, 256, 0, stream>>>(x, nodeW, nodeB, h, ybf);

    for (int l = 0; l < NL; ++l) {
        const float* yin = (l == 0) ? h : y;
        k_agg<<<NN / 4, 256, 0, stream>>>(yin, ybf, rowse, ssrc, tt + l, ag);
        k_gemmA<<<(NN + 63) / 64, 256, 0, stream>>>(ag, W1 + (size_t)l * HH * H2, b1 + (size_t)l * H2, u);
        bool last = (l == NL - 1);
        k_gemmB<<<(NN + 63) / 64, 256, 0, stream>>>(u, W2 + (size_t)l * H2 * HH, b2 + (size_t)l * HH,
                                                    mlg + (size_t)l * H2, mlb + (size_t)l * H2,
                                                    (l == 0) ? (const float*)nullptr : h, h,
                                                    last ? (const float*)nullptr : lng + (size_t)(l + 1) * HH,
                                                    last ? (const float*)nullptr : lnb + (size_t)(l + 1) * HH,
                                                    y, ybf);
    }
    k_outg<<<(NN + 63) / 64, 256, 0, stream>>>(h, lng, lnb, gW, gb, nW, nbp, out, genc);
    k_gdec<<<1, 64, 0, stream>>>(genc, out);
}